// Round 7
// baseline (253.430 us; speedup 1.0000x reference)
//
#include <hip/hip_runtime.h>
#include <hip/hip_bf16.h>

#define B_N 16384
#define D_K 128
#define NBLK 64          // 64 row/col blocks of 256
#define NCHUNK 544       // sum over I of (16 - I/4)

typedef __bf16 bf16x8 __attribute__((ext_vector_type(8)));
typedef float f32x4 __attribute__((ext_vector_type(4)));
typedef float f32x2 __attribute__((ext_vector_type(2)));

#if defined(__has_builtin)
#if __has_builtin(__builtin_amdgcn_exp2f)
#define EXP2F(x) __builtin_amdgcn_exp2f(x)
#else
#define EXP2F(x) exp2f(x)
#endif
#else
#define EXP2F(x) exp2f(x)
#endif

__device__ __forceinline__ void gload_lds16(const void* g, void* l) {
  __builtin_amdgcn_global_load_lds(
      (const __attribute__((address_space(1))) unsigned int*)g,
      (__attribute__((address_space(3))) unsigned int*)l, 16, 0, 0);
}

// ---------------- kernel 1: normalize+prescale rows, build col weights, zero SW
__global__ __launch_bounds__(256) void prep_kernel(
    const float* __restrict__ E, const int* __restrict__ labels,
    const int* __restrict__ mask, __hip_bfloat16* __restrict__ Ebf,
    float2* __restrict__ W, float4* __restrict__ SWz, int nz)
{
  int tid = threadIdx.x;
  int gtid = blockIdx.x * 256 + tid;
  // zero the SW accumulator grid (slot scheme leaves gaps that must read as 0)
  for (int i = gtid; i < nz; i += 262144)
    SWz[i] = make_float4(0.f, 0.f, 0.f, 0.f);
  if (gtid < B_N) {
    int lb = labels[gtid];
    float wm = (mask[gtid] != 0) ? 1.0f : 0.0f;
    W[gtid] = make_float2((lb == 0) ? wm : 0.0f, wm);
  }
  int lane = tid & 63;
  int wid = gtid >> 6;
  const float2* E2 = (const float2*)E;
  __hip_bfloat162* O2 = (__hip_bfloat162*)Ebf;
  for (int row = wid; row < B_N; row += 4096) {
    float2 v = E2[row * 64 + lane];
    float ss = v.x * v.x + v.y * v.y;
    #pragma unroll
    for (int m = 1; m < 64; m <<= 1) ss += __shfl_xor(ss, m);
    // sqrt(14.426950408889634) = sqrt(1/(0.1*ln2)); folded into both operands
    float sc = 3.7982826f / fmaxf(sqrtf(ss), 1e-12f);
    __hip_bfloat162 h;
    h.x = __float2bfloat16(v.x * sc);
    h.y = __float2bfloat16(v.y * sc);
    O2[row * 64 + lane] = h;
  }
}

// ---------------- kernel 2: symmetric chunked Gram
// Block = (I, chunk c): rows of block I x cols of J-blocks [max(I,4c), 4c+4).
// I-side: w(col)-weighted row sums -> slot 4c+3 (always >= I).
// J-side: w(row)-weighted col sums -> slot I (always < J). Disjoint + exact cover.
template<bool DIAG, bool JSIDE>
__device__ __forceinline__ void tile_pair(
    const char* lds, const char* ldsW, const bf16x8 a[4][4],
    const f32x2 wRow[4][4], int C0loc, int colBase, int lane, int WR0,
    f32x2 accI[4][4], f32x2 cs[4])
{
  const int l15 = lane & 15, lg = lane >> 4, l7 = lane & 7;
  #pragma unroll
  for (int nf = 0; nf < 4; ++nf) {   // 4 x 16 = 64 cols
    int col = nf * 16 + l15;
    int colg = colBase + C0loc + col;
    f32x2 wv = *(const f32x2*)(ldsW + ((C0loc + col) << 3));  // w(col) broadcast
    bf16x8 b[4];
    #pragma unroll
    for (int kk = 0; kk < 4; ++kk) {
      int addr = col * 256 + (((kk * 4 + lg) ^ l7) << 4);  // XOR-swizzled chunk
      b[kk] = *(const bf16x8*)(lds + addr);
    }
    f32x4 c[4];
    __builtin_amdgcn_s_setprio(1);
    #pragma unroll
    for (int mf = 0; mf < 4; ++mf) {
      f32x4 t = {0.f, 0.f, 0.f, 0.f};
      #pragma unroll
      for (int kk = 0; kk < 4; ++kk)
        t = __builtin_amdgcn_mfma_f32_16x16x32_bf16(a[mf][kk], b[kk], t, 0, 0, 0);
      c[mf] = t;
    }
    __builtin_amdgcn_s_setprio(0);
    #pragma unroll
    for (int mf = 0; mf < 4; ++mf) {
      #pragma unroll
      for (int r = 0; r < 4; ++r) {
        float p = EXP2F(c[mf][r]);     // exp(sim/T), scale folded into operands
        if (DIAG) {
          int rowg = WR0 + mf * 16 + lg * 4 + r;   // verified C/D layout
          p = (rowg == colg) ? 0.0f : p;
        }
        accI[mf][r] += wv * p;                      // I-side row sums
        if (JSIDE) cs[nf] += wRow[mf][r] * p;       // J-side col sums
      }
    }
  }
}

__global__ __launch_bounds__(256, 2) void gemm_chunk(
    const __hip_bfloat16* __restrict__ Ebf, const float2* __restrict__ W,
    float2* __restrict__ SW)
{
  __shared__ alignas(16) char smem[73728];
  char* ldsW = smem;                       // 8 KB: w(col) for up to 1024 cols
  float2* cbuf = (float2*)(smem + 8192);   // 32 KB: [4 waves][1024 cols]
  char* dbuf = smem + 40960;               // 2 x 16 KB tile double-buffer

  const int tid = threadIdx.x;
  const int lane = tid & 63;
  const int w = tid >> 6;
  const int l15 = lane & 15, lg = lane >> 4;

  // decode (I, c): chunks per I = 16 - I/4; natural order = big blocks first
  int b = blockIdx.x, I = 0;
  while (b >= 16 - (I >> 2)) { b -= 16 - (I >> 2); ++I; }
  const int c = (I >> 2) + b;
  const int J0 = (4 * c > I) ? 4 * c : I;
  const int colBase = J0 << 8;
  const int ncols = (4 * c + 4 - J0) << 8;   // 256..1024
  const int nt = ncols >> 6;                 // 4..16 tiles

  const int R0 = I << 8;
  const int WR0 = R0 + w * 64;   // this wave's 64 rows of block I

  // A fragments (once per block, amortized over up to 16 tiles)
  bf16x8 a[4][4];
  #pragma unroll
  for (int mf = 0; mf < 4; ++mf)
    #pragma unroll
    for (int kk = 0; kk < 4; ++kk) {
      int row = WR0 + mf * 16 + l15;
      a[mf][kk] = *(const bf16x8*)(Ebf + (size_t)row * D_K + kk * 32 + lg * 8);
    }
  f32x2 wRow[4][4];              // w(row) for this lane's 16 accumulator rows
  #pragma unroll
  for (int mf = 0; mf < 4; ++mf)
    #pragma unroll
    for (int r = 0; r < 4; ++r)
      wRow[mf][r] = *(const f32x2*)&W[WR0 + mf * 16 + lg * 4 + r];

  // staging offsets: linear LDS dest, swizzle on the GLOBAL source (m173 pattern)
  int goff[4], loff[4];
  #pragma unroll
  for (int i = 0; i < 4; ++i) {
    int q = i * 4 + w;
    int col = q * 4 + lg;
    int cc = l15 ^ (col & 7);
    goff[i] = col * D_K + cc * 8;
    loff[i] = q * 1024;
  }

  // stage w(col) slice (ncols*8 bytes in 16B chunks)
  {
    const char* wsrc = (const char*)(W + colBase);
    for (int i = tid; i < (ncols >> 1); i += 256)
      gload_lds16(wsrc + i * 16, ldsW + i * 16);
  }
  // stage tile 0
  {
    const __hip_bfloat16* s0p = Ebf + (size_t)colBase * D_K;
    #pragma unroll
    for (int i = 0; i < 4; ++i) gload_lds16(s0p + goff[i], dbuf + loff[i]);
  }
  asm volatile("s_waitcnt vmcnt(0)" ::: "memory");
  __builtin_amdgcn_s_barrier();

  f32x2 accI[4][4] = {};
  int cur = 0;
  for (int t = 0; t < nt; ++t) {
    if (t + 1 < nt) {   // prefetch next tile into the other buffer (R2-proven 2-phase)
      const __hip_bfloat16* src = Ebf + (size_t)(colBase + ((t + 1) << 6)) * D_K;
      char* dst = dbuf + ((cur ^ 1) << 14);
      #pragma unroll
      for (int i = 0; i < 4; ++i) gload_lds16(src + goff[i], dst + loff[i]);
    }
    const int C0loc = t << 6;
    const char* lds = dbuf + (cur << 14);
    const int jb = (colBase + C0loc) >> 8;
    f32x2 cs[4] = {};
    if (jb == I) {
      tile_pair<true, false>(lds, ldsW, a, wRow, C0loc, colBase, lane, WR0, accI, cs);
    } else {
      tile_pair<false, true>(lds, ldsW, a, wRow, C0loc, colBase, lane, WR0, accI, cs);
      // intra-wave col-sum reduce (over lane groups) -> per-wave LDS strip
      #pragma unroll
      for (int nf = 0; nf < 4; ++nf) {
        float x = cs[nf].x, y = cs[nf].y;
        x += __shfl_xor(x, 16); x += __shfl_xor(x, 32);
        y += __shfl_xor(y, 16); y += __shfl_xor(y, 32);
        if (lg == nf) cbuf[w * 1024 + C0loc + nf * 16 + l15] = make_float2(x, y);
      }
    }
    asm volatile("s_waitcnt vmcnt(0)" ::: "memory");
    __builtin_amdgcn_s_barrier();
    cur ^= 1;
  }

  // I-side write: slot 4c+3, rows of I
  #pragma unroll
  for (int mf = 0; mf < 4; ++mf) {
    #pragma unroll
    for (int r = 0; r < 4; ++r) {
      float s0 = accI[mf][r].x, tt = accI[mf][r].y;
      #pragma unroll
      for (int m = 1; m < 16; m <<= 1) {
        s0 += __shfl_xor(s0, m);
        tt += __shfl_xor(tt, m);
      }
      if (l15 == 0) {
        int rowg = WR0 + mf * 16 + lg * 4 + r;
        SW[(size_t)(4 * c + 3) * B_N + rowg] = make_float2(s0, tt);
      }
    }
  }

  // J-side write: slot I, rows of the chunk's J-blocks (cross-wave sum via LDS)
  __syncthreads();
  for (int col = tid; col < ncols; col += 256) {
    int colg = colBase + col;
    if ((colg >> 8) != I) {
      float2 v0 = cbuf[col], v1 = cbuf[1024 + col];
      float2 v2 = cbuf[2048 + col], v3 = cbuf[3072 + col];
      SW[(size_t)I * B_N + colg] =
          make_float2(v0.x + v1.x + v2.x + v3.x, v0.y + v1.y + v2.y + v3.y);
    }
  }
}

// ---------------- fallback kernel 2 (R5 split version, used only if workspace is tight)
template<bool DIAG>
__device__ __forceinline__ void tile_compute(
    const char* lds, const char* ldsW, const bf16x8 a[4][4],
    int C0loc, int colBase, int lane, int WR0,
    f32x2 acc[4][4])
{
  const int l15 = lane & 15, lg = lane >> 4, l7 = lane & 7;
  #pragma unroll
  for (int nf = 0; nf < 4; ++nf) {
    int col = nf * 16 + l15;
    int colg = colBase + C0loc + col;
    f32x2 wv = *(const f32x2*)(ldsW + ((C0loc + col) << 3));
    bf16x8 b[4];
    #pragma unroll
    for (int kk = 0; kk < 4; ++kk) {
      int addr = col * 256 + (((kk * 4 + lg) ^ l7) << 4);
      b[kk] = *(const bf16x8*)(lds + addr);
    }
    f32x4 c[4];
    __builtin_amdgcn_s_setprio(1);
    #pragma unroll
    for (int mf = 0; mf < 4; ++mf) {
      f32x4 t = {0.f, 0.f, 0.f, 0.f};
      #pragma unroll
      for (int kk = 0; kk < 4; ++kk)
        t = __builtin_amdgcn_mfma_f32_16x16x32_bf16(a[mf][kk], b[kk], t, 0, 0, 0);
      c[mf] = t;
    }
    __builtin_amdgcn_s_setprio(0);
    #pragma unroll
    for (int mf = 0; mf < 4; ++mf) {
      #pragma unroll
      for (int r = 0; r < 4; ++r) {
        float p = EXP2F(c[mf][r]);
        if (DIAG) {
          int rowg = WR0 + mf * 16 + lg * 4 + r;
          p = (rowg == colg) ? 0.0f : p;
        }
        acc[mf][r] += wv * p;
      }
    }
  }
}

__global__ __launch_bounds__(256, 2) void gemm_kernel(
    const __hip_bfloat16* __restrict__ Ebf, const float2* __restrict__ W,
    float2* __restrict__ SW, int colsPerSplit)
{
  __shared__ alignas(16) char smem[65536];
  char* ldsW  = smem;
  char* tiles = smem + 16384;

  const int tid = threadIdx.x;
  const int lane = tid & 63;
  const int w = tid >> 6;
  const int R0 = blockIdx.x * 256;
  const int WR0 = R0 + w * 64;
  const int l15 = lane & 15, lg = lane >> 4;

  bf16x8 a[4][4];
  #pragma unroll
  for (int mf = 0; mf < 4; ++mf)
    #pragma unroll
    for (int kk = 0; kk < 4; ++kk) {
      int row = WR0 + mf * 16 + l15;
      a[mf][kk] = *(const bf16x8*)(Ebf + (size_t)row * D_K + kk * 32 + lg * 8);
    }

  int goff[4], loff[4];
  #pragma unroll
  for (int i = 0; i < 4; ++i) {
    int q = i * 4 + w;
    int col = q * 4 + lg;
    int cc = l15 ^ (col & 7);
    goff[i] = col * D_K + cc * 8;
    loff[i] = q * 1024;
  }

  f32x2 acc[4][4] = {};
  const int colBase = blockIdx.y * colsPerSplit;
  const int nt = colsPerSplit >> 6;

  {
    const char* wsrc = (const char*)(W + colBase);
    int nW = colsPerSplit >> 9;
    for (int i = 0; i < nW; ++i)
      gload_lds16(wsrc + (((i * 4 + w) * 64 + lane) << 4), ldsW + ((i * 4 + w) << 10));
  }
  {
    const __hip_bfloat16* src0 = Ebf + (size_t)colBase * D_K;
    #pragma unroll
    for (int i = 0; i < 4; ++i) gload_lds16(src0 + goff[i], tiles + loff[i]);
  }
  asm volatile("s_waitcnt vmcnt(0)" ::: "memory");
  __builtin_amdgcn_s_barrier();

  int cur = 0;
  for (int t = 0; t < nt; ++t) {
    if (t + 1 < nt) {
      const __hip_bfloat16* src = Ebf + (size_t)(colBase + ((t + 1) << 6)) * D_K;
      #pragma unroll
      for (int i = 0; i < 4; ++i) gload_lds16(src + goff[i], tiles + ((cur ^ 1) << 14) + loff[i]);
    }
    const int C0loc = t << 6;
    const int Cg = colBase + C0loc;
    const bool diag = (Cg < R0 + 256) && (Cg + 64 > R0);
    if (diag) tile_compute<true >(tiles + (cur << 14), ldsW, a, C0loc, colBase, lane, WR0, acc);
    else      tile_compute<false>(tiles + (cur << 14), ldsW, a, C0loc, colBase, lane, WR0, acc);
    asm volatile("s_waitcnt vmcnt(0)" ::: "memory");
    __builtin_amdgcn_s_barrier();
    cur ^= 1;
  }

  #pragma unroll
  for (int mf = 0; mf < 4; ++mf) {
    #pragma unroll
    for (int r = 0; r < 4; ++r) {
      float s0 = acc[mf][r].x, tt = acc[mf][r].y;
      #pragma unroll
      for (int m = 1; m < 16; m <<= 1) {
        s0 += __shfl_xor(s0, m);
        tt += __shfl_xor(tt, m);
      }
      if (l15 == 0) {
        int rowg = WR0 + mf * 16 + lg * 4 + r;
        SW[(size_t)blockIdx.y * B_N + rowg] = make_float2(s0, tt);
      }
    }
  }
}

// ---------------- kernel 3a: per-row loss, 256 blocks x 64 rows, deterministic
__global__ __launch_bounds__(256) void loss_part(
    const int* __restrict__ labels, const int* __restrict__ mask,
    const float2* __restrict__ SW, int NS, float2* __restrict__ partial)
{
  __shared__ int sc0[4], sc1[4];
  __shared__ float st[4], sn[4];
  __shared__ float2 red[256];
  int tid = threadIdx.x, lane = tid & 63, wv = tid >> 6;

  // redundant full histogram per block (L2-resident, deterministic)
  int c0 = 0, c1 = 0;
  for (int i = tid; i < B_N; i += 256) {
    if (mask[i] != 0) { if (labels[i] == 0) c0++; else c1++; }
  }
  #pragma unroll
  for (int m = 1; m < 64; m <<= 1) { c0 += __shfl_xor(c0, m); c1 += __shfl_xor(c1, m); }
  if (lane == 0) { sc0[wv] = c0; sc1[wv] = c1; }
  __syncthreads();
  int cnt0 = sc0[0] + sc0[1] + sc0[2] + sc0[3];
  int cnt1 = sc1[0] + sc1[1] + sc1[2] + sc1[3];

  // 64 rows per block; 4 threads per row (slot quarters), fixed-order combine
  int r = blockIdx.x * 64 + (tid & 63);
  int q = tid >> 6;
  float s0 = 0.f, tt = 0.f;
  for (int s = q; s < NS; s += 4) {
    float2 v = SW[(size_t)s * B_N + r];
    s0 += v.x; tt += v.y;
  }
  red[tid] = make_float2(s0, tt);
  __syncthreads();

  float tot = 0.f, nv = 0.f;
  if (q == 0) {
    float2 va = red[tid], vb = red[64 + tid], vc = red[128 + tid], vd = red[192 + tid];
    s0 = va.x + vb.x + vc.x + vd.x;
    tt = va.y + vb.y + vc.y + vd.y;
    int lb = labels[r];
    float pos = (lb == 0) ? s0 : (tt - s0);
    int cnt = (lb == 0) ? cnt0 : cnt1;
    if (mask[r] != 0 && cnt > 1) {
      // den = pos + neg = tt (diag excluded); loss = log(den+EPS) - log(pos)
      tot = logf(tt + 1e-8f) - logf(pos);
      nv = 1.f;
    }
  }
  #pragma unroll
  for (int m = 1; m < 64; m <<= 1) { tot += __shfl_xor(tot, m); nv += __shfl_xor(nv, m); }
  if (lane == 0) { st[wv] = tot; sn[wv] = nv; }
  __syncthreads();
  if (tid == 0) {
    partial[blockIdx.x] = make_float2(st[0] + st[1] + st[2] + st[3],
                                      sn[0] + sn[1] + sn[2] + sn[3]);
  }
}

// ---------------- kernel 3b: final deterministic reduce (one wave)
__global__ __launch_bounds__(64) void loss_final(
    const float2* __restrict__ partial, int nb, float* __restrict__ out)
{
  int lane = threadIdx.x;
  float t = 0.f, n = 0.f;
  for (int i = lane; i < nb; i += 64) {
    float2 v = partial[i];
    t += v.x; n += v.y;
  }
  #pragma unroll
  for (int m = 1; m < 64; m <<= 1) { t += __shfl_xor(t, m); n += __shfl_xor(n, m); }
  if (lane == 0) out[0] = (n > 0.f) ? t / fmaxf(n, 1.f) : 0.f;
}

extern "C" void kernel_launch(void* const* d_in, const int* in_sizes, int n_in,
                              void* d_out, int out_size, void* d_ws, size_t ws_size,
                              hipStream_t stream)
{
  const float* E = (const float*)d_in[0];
  const int* labels = (const int*)d_in[1];
  const int* mask = (const int*)d_in[2];

  char* ws = (char*)d_ws;
  __hip_bfloat16* Ebf = (__hip_bfloat16*)ws;                       // 4 MB
  float2* W = (float2*)(ws + (size_t)B_N * D_K * 2);               // 128 KB
  float2* SW = (float2*)(ws + (size_t)B_N * D_K * 2 + (size_t)B_N * 8);
  size_t base = (size_t)B_N * D_K * 2 + (size_t)B_N * 8;

  size_t needSym = base + (size_t)NBLK * B_N * 8 + 4096;
  if (ws_size >= needSym) {
    // symmetric chunked path: 544 blocks, up to 16 tiles each
    float2* partial = (float2*)(ws + base + (size_t)NBLK * B_N * 8);
    prep_kernel<<<1024, 256, 0, stream>>>(E, labels, mask, Ebf, W,
                                          (float4*)SW, NBLK * (B_N / 2));
    gemm_chunk<<<NCHUNK, 256, 0, stream>>>(Ebf, W, SW);
    loss_part<<<B_N / 64, 256, 0, stream>>>(labels, mask, SW, NBLK, partial);
    loss_final<<<1, 64, 0, stream>>>(partial, B_N / 64, (float*)d_out);
  } else {
    // fallback: non-symmetric col-split path (R5)
    int NS = 16;
    while (NS > 8 && base + (size_t)NS * B_N * 8 + 4096 > ws_size) NS >>= 1;
    int cps = B_N / NS;
    float2* partial = (float2*)(ws + base + (size_t)NS * B_N * 8);
    prep_kernel<<<1024, 256, 0, stream>>>(E, labels, mask, Ebf, W,
                                          (float4*)SW, NS * (B_N / 2));
    dim3 g2(B_N / 256, NS);
    gemm_kernel<<<g2, 256, 0, stream>>>(Ebf, W, SW, cps);
    loss_part<<<B_N / 64, 256, 0, stream>>>(labels, mask, SW, NS, partial);
    loss_final<<<1, 64, 0, stream>>>(partial, B_N / 64, (float*)d_out);
  }
}

// Round 8
// 238.208 us; speedup vs baseline: 1.0639x; 1.0639x over previous
//
#include <hip/hip_runtime.h>
#include <hip/hip_bf16.h>

#define B_N 16384
#define D_K 128
#define NSYM 544   // 496 full + 16x12t + 16x8t + 16x4t symmetric chunks

typedef __bf16 bf16x8 __attribute__((ext_vector_type(8)));
typedef float f32x4 __attribute__((ext_vector_type(4)));
typedef float f32x2 __attribute__((ext_vector_type(2)));

#if defined(__has_builtin)
#if __has_builtin(__builtin_amdgcn_exp2f)
#define EXP2F(x) __builtin_amdgcn_exp2f(x)
#else
#define EXP2F(x) exp2f(x)
#endif
#else
#define EXP2F(x) exp2f(x)
#endif

__device__ __forceinline__ void gload_lds16(const void* g, void* l) {
  __builtin_amdgcn_global_load_lds(
      (const __attribute__((address_space(1))) unsigned int*)g,
      (__attribute__((address_space(3))) unsigned int*)l, 16, 0, 0);
}

// ---------------- kernel 1: normalize rows, prescale by sqrt(1/(T*ln2)), build col weights
__global__ __launch_bounds__(256) void prep_kernel(
    const float* __restrict__ E, const int* __restrict__ labels,
    const int* __restrict__ mask, __hip_bfloat16* __restrict__ Ebf,
    float2* __restrict__ W)
{
  int tid = threadIdx.x;
  int gtid = blockIdx.x * 256 + tid;
  if (gtid < B_N) {
    int lb = labels[gtid];
    float wm = (mask[gtid] != 0) ? 1.0f : 0.0f;
    W[gtid] = make_float2((lb == 0) ? wm : 0.0f, wm);
  }
  int lane = tid & 63;
  int wid = gtid >> 6;
  const float2* E2 = (const float2*)E;
  __hip_bfloat162* O2 = (__hip_bfloat162*)Ebf;
  for (int row = wid; row < B_N; row += 4096) {
    float2 v = E2[row * 64 + lane];
    float ss = v.x * v.x + v.y * v.y;
    #pragma unroll
    for (int m = 1; m < 64; m <<= 1) ss += __shfl_xor(ss, m);
    float sc = 3.7982826f / fmaxf(sqrtf(ss), 1e-12f);
    __hip_bfloat162 h;
    h.x = __float2bfloat16(v.x * sc);
    h.y = __float2bfloat16(v.y * sc);
    O2[row * 64 + lane] = h;
  }
}

// ---------------- symmetric chunk tile body (R7-proven numerics)
template<bool DIAG, bool JSIDE>
__device__ __forceinline__ void tile_pair(
    const char* lds, const char* ldsW, const bf16x8 a[4][4],
    const f32x2 wRow[4][4], int C0loc, int colBase, int lane, int WR0,
    f32x2 accI[4][4], f32x2 cs[4])
{
  const int l15 = lane & 15, lg = lane >> 4, l7 = lane & 7;
  #pragma unroll
  for (int nf = 0; nf < 4; ++nf) {
    int col = nf * 16 + l15;
    int colg = colBase + C0loc + col;
    f32x2 wv = *(const f32x2*)(ldsW + ((C0loc + col) << 3));
    bf16x8 b[4];
    #pragma unroll
    for (int kk = 0; kk < 4; ++kk) {
      int addr = col * 256 + (((kk * 4 + lg) ^ l7) << 4);
      b[kk] = *(const bf16x8*)(lds + addr);
    }
    f32x4 c[4];
    __builtin_amdgcn_s_setprio(1);
    #pragma unroll
    for (int mf = 0; mf < 4; ++mf) {
      f32x4 t = {0.f, 0.f, 0.f, 0.f};
      #pragma unroll
      for (int kk = 0; kk < 4; ++kk)
        t = __builtin_amdgcn_mfma_f32_16x16x32_bf16(a[mf][kk], b[kk], t, 0, 0, 0);
      c[mf] = t;
    }
    __builtin_amdgcn_s_setprio(0);
    #pragma unroll
    for (int mf = 0; mf < 4; ++mf) {
      #pragma unroll
      for (int r = 0; r < 4; ++r) {
        float p = EXP2F(c[mf][r]);
        if (DIAG) {
          int rowg = WR0 + mf * 16 + lg * 4 + r;
          p = (rowg == colg) ? 0.0f : p;
        }
        accI[mf][r] += wv * p;                 // I-side row sums
        if (JSIDE) cs[nf] += wRow[mf][r] * p;  // J-side col sums
      }
    }
  }
}

// ---------------- kernel 2: symmetric chunked Gram, ring-3 counted-vmcnt pipeline
// ordering: bids 0..495 full chunks (I<=4c, c-major), 496..511 I=4c+1 (12t),
// 512..527 I=4c+2 (8t), 528..543 I=4c+3 (4t)  [tail-balanced to 512 capacity]
// I-side -> slot 4c+3 (rows of I); J-side -> slot I (cols).  Row r, block R reads
// slots s<R (J-side) and s>=R with s%4==3 (I-side) -- exact cover, no zeroing.
__global__ __launch_bounds__(256, 2) void gemm_sym(
    const __hip_bfloat16* __restrict__ Ebf, const float2* __restrict__ W,
    float2* __restrict__ SW)
{
  __shared__ alignas(16) char smem[67584];
  char* ring = smem;                           // 3 x 16 KB tile ring
  f32x2* strip = (f32x2*)(smem + 49152);       // 2 KB: per-tile per-wave col sums
  f32x2* total = (f32x2*)(smem + 51200);       // 8 KB: running J-side col sums
  char* ldsW = smem + 59392;                   // 8 KB: w(col) slice

  const int tid = threadIdx.x;
  const int lane = tid & 63;
  const int w = tid >> 6;
  const int l15 = lane & 15, lg = lane >> 4;

  // ---- decode bid -> (c, I)
  int bid = blockIdx.x, c, I;
  if (bid < 496) {                  // full chunks: offset(c) = 2c^2 - c, count 4c+1
    int k = bid;
    c = (int)((1.0f + sqrtf(1.0f + 8.0f * (float)k)) * 0.25f);
    while (2 * c * c - c > k) --c;
    while (2 * (c + 1) * (c + 1) - (c + 1) <= k) ++c;
    I = k - (2 * c * c - c);
  } else if (bid < 512) { c = bid - 496; I = 4 * c + 1; }
  else if (bid < 528)   { c = bid - 512; I = 4 * c + 2; }
  else                  { c = bid - 528; I = 4 * c + 3; }

  const int J0b = (4 * c > I) ? 4 * c : I;
  const int colBase = J0b << 8;
  const int ncols = (4 * c + 4 - J0b) << 8;   // 256..1024
  const int nt = ncols >> 6;                  // 4..16
  const int R0 = I << 8;
  const int WR0 = R0 + w * 64;

  // ---- prologue register loads (older than all stages in vmcnt order)
  bf16x8 a[4][4];
  #pragma unroll
  for (int mf = 0; mf < 4; ++mf)
    #pragma unroll
    for (int kk = 0; kk < 4; ++kk) {
      int row = WR0 + mf * 16 + l15;
      a[mf][kk] = *(const bf16x8*)(Ebf + (size_t)row * D_K + kk * 32 + lg * 8);
    }
  f32x2 wRow[4][4];
  #pragma unroll
  for (int mf = 0; mf < 4; ++mf)
    #pragma unroll
    for (int r = 0; r < 4; ++r)
      wRow[mf][r] = *(const f32x2*)&W[WR0 + mf * 16 + lg * 4 + r];

  // clear J-side running totals (synced by first __syncthreads)
  for (int i = tid; i < (ncols); i += 256) total[i] = f32x2{0.f, 0.f};

  // staging offsets: linear LDS dest, swizzle on the GLOBAL source
  int goff[4], loff[4];
  #pragma unroll
  for (int i = 0; i < 4; ++i) {
    int q = i * 4 + w;
    int col = q * 4 + lg;
    int cc = l15 ^ (col & 7);
    goff[i] = col * D_K + cc * 8;
    loff[i] = q * 1024;
  }

  // stage W slice, then tiles 0 and 1 (W + tile0 retired by first vmcnt(4))
  {
    const char* wsrc = (const char*)(W + colBase);
    for (int i = tid; i < (ncols >> 1); i += 256)
      gload_lds16(wsrc + i * 16, ldsW + i * 16);
    const __hip_bfloat16* s0p = Ebf + (size_t)colBase * D_K;
    #pragma unroll
    for (int i = 0; i < 4; ++i) gload_lds16(s0p + goff[i], ring + loff[i]);
    const __hip_bfloat16* s1p = Ebf + (size_t)(colBase + 64) * D_K;
    #pragma unroll
    for (int i = 0; i < 4; ++i) gload_lds16(s1p + goff[i], ring + 16384 + loff[i]);
  }

  f32x2 accI[4][4] = {};
  for (int t = 0; t < nt; ++t) {
    // counted wait: leave only the newest 4 (stage t+1) in flight
    if (t + 1 < nt) asm volatile("s_waitcnt vmcnt(4)" ::: "memory");
    else            asm volatile("s_waitcnt vmcnt(0)" ::: "memory");
    __builtin_amdgcn_s_barrier();            // A_t: tile t complete for all waves
    asm volatile("" ::: "memory");
    if (t + 2 < nt) {                        // 2-phase-deep prefetch (miss-latency cover)
      const __hip_bfloat16* src = Ebf + (size_t)(colBase + ((t + 2) << 6)) * D_K;
      char* dst = ring + ((t + 2) % 3) * 16384;
      #pragma unroll
      for (int i = 0; i < 4; ++i) gload_lds16(src + goff[i], dst + loff[i]);
    }
    const char* lds = ring + (t % 3) * 16384;
    const int jb = (colBase + (t << 6)) >> 8;
    const bool diagT = (jb == I);
    f32x2 cs[4] = {};
    if (diagT)
      tile_pair<true,  false>(lds, ldsW, a, wRow, t << 6, colBase, lane, WR0, accI, cs);
    else {
      tile_pair<false, true >(lds, ldsW, a, wRow, t << 6, colBase, lane, WR0, accI, cs);
      #pragma unroll
      for (int nf = 0; nf < 4; ++nf) {       // intra-wave col-sum reduce -> strip
        float x = cs[nf].x, y = cs[nf].y;
        x += __shfl_xor(x, 16); x += __shfl_xor(x, 32);
        y += __shfl_xor(y, 16); y += __shfl_xor(y, 32);
        if (lg == nf) strip[w * 64 + nf * 16 + l15] = f32x2{x, y};
      }
    }
    __syncthreads();                         // B_t: strips stable
    if (!diagT && tid < 64) {                // wave0 accumulates before A_{t+1}
      f32x2 s = strip[tid];
      s += strip[64 + tid]; s += strip[128 + tid]; s += strip[192 + tid];
      total[(t << 6) + tid] += s;
    }
  }

  // I-side write: slot 4c+3, rows of I
  #pragma unroll
  for (int mf = 0; mf < 4; ++mf) {
    #pragma unroll
    for (int r = 0; r < 4; ++r) {
      float s0 = accI[mf][r].x, tt = accI[mf][r].y;
      #pragma unroll
      for (int m = 1; m < 16; m <<= 1) {
        s0 += __shfl_xor(s0, m);
        tt += __shfl_xor(tt, m);
      }
      if (l15 == 0) {
        int rowg = WR0 + mf * 16 + lg * 4 + r;
        SW[(size_t)(4 * c + 3) * B_N + rowg] = make_float2(s0, tt);
      }
    }
  }

  // J-side write: slot I (skip diag-block cols)
  __syncthreads();
  for (int col = tid; col < ncols; col += 256) {
    int colg = colBase + col;
    if ((colg >> 8) != I) {
      f32x2 v = total[col];
      SW[(size_t)I * B_N + colg] = make_float2(v.x, v.y);
    }
  }
}

// ---------------- fallback kernel 2 (R5 split version)
template<bool DIAG>
__device__ __forceinline__ void tile_compute(
    const char* lds, const char* ldsW, const bf16x8 a[4][4],
    int C0loc, int colBase, int lane, int WR0, f32x2 acc[4][4])
{
  const int l15 = lane & 15, lg = lane >> 4, l7 = lane & 7;
  #pragma unroll
  for (int nf = 0; nf < 4; ++nf) {
    int col = nf * 16 + l15;
    int colg = colBase + C0loc + col;
    f32x2 wv = *(const f32x2*)(ldsW + ((C0loc + col) << 3));
    bf16x8 b[4];
    #pragma unroll
    for (int kk = 0; kk < 4; ++kk) {
      int addr = col * 256 + (((kk * 4 + lg) ^ l7) << 4);
      b[kk] = *(const bf16x8*)(lds + addr);
    }
    f32x4 c[4];
    #pragma unroll
    for (int mf = 0; mf < 4; ++mf) {
      f32x4 t = {0.f, 0.f, 0.f, 0.f};
      #pragma unroll
      for (int kk = 0; kk < 4; ++kk)
        t = __builtin_amdgcn_mfma_f32_16x16x32_bf16(a[mf][kk], b[kk], t, 0, 0, 0);
      c[mf] = t;
    }
    #pragma unroll
    for (int mf = 0; mf < 4; ++mf) {
      #pragma unroll
      for (int r = 0; r < 4; ++r) {
        float p = EXP2F(c[mf][r]);
        if (DIAG) {
          int rowg = WR0 + mf * 16 + lg * 4 + r;
          p = (rowg == colg) ? 0.0f : p;
        }
        acc[mf][r] += wv * p;
      }
    }
  }
}

__global__ __launch_bounds__(256, 2) void gemm_kernel(
    const __hip_bfloat16* __restrict__ Ebf, const float2* __restrict__ W,
    float2* __restrict__ SW, int colsPerSplit)
{
  __shared__ alignas(16) char smem[65536];
  char* ldsW  = smem;
  char* tiles = smem + 16384;
  const int tid = threadIdx.x;
  const int lane = tid & 63;
  const int w = tid >> 6;
  const int R0 = blockIdx.x * 256;
  const int WR0 = R0 + w * 64;
  const int l15 = lane & 15, lg = lane >> 4;

  bf16x8 a[4][4];
  #pragma unroll
  for (int mf = 0; mf < 4; ++mf)
    #pragma unroll
    for (int kk = 0; kk < 4; ++kk) {
      int row = WR0 + mf * 16 + l15;
      a[mf][kk] = *(const bf16x8*)(Ebf + (size_t)row * D_K + kk * 32 + lg * 8);
    }
  int goff[4], loff[4];
  #pragma unroll
  for (int i = 0; i < 4; ++i) {
    int q = i * 4 + w;
    int col = q * 4 + lg;
    int cc = l15 ^ (col & 7);
    goff[i] = col * D_K + cc * 8;
    loff[i] = q * 1024;
  }
  f32x2 acc[4][4] = {};
  const int colBase = blockIdx.y * colsPerSplit;
  const int nt = colsPerSplit >> 6;
  {
    const char* wsrc = (const char*)(W + colBase);
    for (int i = tid; i < (colsPerSplit >> 1); i += 256)
      gload_lds16(wsrc + i * 16, ldsW + i * 16);
    const __hip_bfloat16* src0 = Ebf + (size_t)colBase * D_K;
    #pragma unroll
    for (int i = 0; i < 4; ++i) gload_lds16(src0 + goff[i], tiles + loff[i]);
  }
  asm volatile("s_waitcnt vmcnt(0)" ::: "memory");
  __builtin_amdgcn_s_barrier();
  int cur = 0;
  for (int t = 0; t < nt; ++t) {
    if (t + 1 < nt) {
      const __hip_bfloat16* src = Ebf + (size_t)(colBase + ((t + 1) << 6)) * D_K;
      #pragma unroll
      for (int i = 0; i < 4; ++i) gload_lds16(src + goff[i], tiles + ((cur ^ 1) << 14) + loff[i]);
    }
    const int C0loc = t << 6;
    const int Cg = colBase + C0loc;
    const bool diag = (Cg < R0 + 256) && (Cg + 64 > R0);
    if (diag) tile_compute<true >(tiles + (cur << 14), ldsW, a, C0loc, colBase, lane, WR0, acc);
    else      tile_compute<false>(tiles + (cur << 14), ldsW, a, C0loc, colBase, lane, WR0, acc);
    asm volatile("s_waitcnt vmcnt(0)" ::: "memory");
    __builtin_amdgcn_s_barrier();
    cur ^= 1;
  }
  #pragma unroll
  for (int mf = 0; mf < 4; ++mf) {
    #pragma unroll
    for (int r = 0; r < 4; ++r) {
      float s0 = acc[mf][r].x, tt = acc[mf][r].y;
      #pragma unroll
      for (int m = 1; m < 16; m <<= 1) { s0 += __shfl_xor(s0, m); tt += __shfl_xor(tt, m); }
      if (l15 == 0) {
        int rowg = WR0 + mf * 16 + lg * 4 + r;
        SW[(size_t)blockIdx.y * B_N + rowg] = make_float2(s0, tt);
      }
    }
  }
}

// ---------------- kernel 3a: per-row loss (symMode: read only written slots)
__global__ __launch_bounds__(256) void loss_part(
    const int* __restrict__ labels, const int* __restrict__ mask,
    const float2* __restrict__ SW, int NS, int symMode, float2* __restrict__ partial)
{
  __shared__ int sc0[4], sc1[4];
  __shared__ float st[4], sn[4];
  __shared__ float2 red[256];
  int tid = threadIdx.x, lane = tid & 63, wv = tid >> 6;

  int c0 = 0, c1 = 0;
  for (int i = tid; i < B_N; i += 256) {
    if (mask[i] != 0) { if (labels[i] == 0) c0++; else c1++; }
  }
  #pragma unroll
  for (int m = 1; m < 64; m <<= 1) { c0 += __shfl_xor(c0, m); c1 += __shfl_xor(c1, m); }
  if (lane == 0) { sc0[wv] = c0; sc1[wv] = c1; }
  __syncthreads();
  int cnt0 = sc0[0] + sc0[1] + sc0[2] + sc0[3];
  int cnt1 = sc1[0] + sc1[1] + sc1[2] + sc1[3];

  int r = blockIdx.x * 64 + (tid & 63);
  int q = tid >> 6;
  int R = r >> 8;
  float s0 = 0.f, tt = 0.f;
  for (int s = q; s < NS; s += 4) {
    bool use = symMode ? ((s < R) || (((s & 3) == 3) && s >= R)) : true;
    if (use) {
      float2 v = SW[(size_t)s * B_N + r];
      s0 += v.x; tt += v.y;
    }
  }
  red[tid] = make_float2(s0, tt);
  __syncthreads();

  float tot = 0.f, nv = 0.f;
  if (q == 0) {
    float2 va = red[tid], vb = red[64 + tid], vc = red[128 + tid], vd = red[192 + tid];
    s0 = va.x + vb.x + vc.x + vd.x;
    tt = va.y + vb.y + vc.y + vd.y;
    int lb = labels[r];
    float pos = (lb == 0) ? s0 : (tt - s0);
    int cnt = (lb == 0) ? cnt0 : cnt1;
    if (mask[r] != 0 && cnt > 1) {
      tot = logf(tt + 1e-8f) - logf(pos);
      nv = 1.f;
    }
  }
  #pragma unroll
  for (int m = 1; m < 64; m <<= 1) { tot += __shfl_xor(tot, m); nv += __shfl_xor(nv, m); }
  if (lane == 0) { st[wv] = tot; sn[wv] = nv; }
  __syncthreads();
  if (tid == 0) {
    partial[blockIdx.x] = make_float2(st[0] + st[1] + st[2] + st[3],
                                      sn[0] + sn[1] + sn[2] + sn[3]);
  }
}

// ---------------- kernel 3b: final deterministic reduce (one wave)
__global__ __launch_bounds__(64) void loss_final(
    const float2* __restrict__ partial, int nb, float* __restrict__ out)
{
  int lane = threadIdx.x;
  float t = 0.f, n = 0.f;
  for (int i = lane; i < nb; i += 64) {
    float2 v = partial[i];
    t += v.x; n += v.y;
  }
  #pragma unroll
  for (int m = 1; m < 64; m <<= 1) { t += __shfl_xor(t, m); n += __shfl_xor(n, m); }
  if (lane == 0) out[0] = (n > 0.f) ? t / fmaxf(n, 1.f) : 0.f;
}

extern "C" void kernel_launch(void* const* d_in, const int* in_sizes, int n_in,
                              void* d_out, int out_size, void* d_ws, size_t ws_size,
                              hipStream_t stream)
{
  const float* E = (const float*)d_in[0];
  const int* labels = (const int*)d_in[1];
  const int* mask = (const int*)d_in[2];

  char* ws = (char*)d_ws;
  __hip_bfloat16* Ebf = (__hip_bfloat16*)ws;                       // 4 MB
  float2* W = (float2*)(ws + (size_t)B_N * D_K * 2);               // 128 KB
  float2* SW = (float2*)(ws + (size_t)B_N * D_K * 2 + (size_t)B_N * 8);
  size_t base = (size_t)B_N * D_K * 2 + (size_t)B_N * 8;

  prep_kernel<<<1024, 256, 0, stream>>>(E, labels, mask, Ebf, W);

  size_t needSym = base + (size_t)64 * B_N * 8 + 4096;
  if (ws_size >= needSym) {
    float2* partial = (float2*)(ws + base + (size_t)64 * B_N * 8);
    gemm_sym<<<NSYM, 256, 0, stream>>>(Ebf, W, SW);
    loss_part<<<B_N / 64, 256, 0, stream>>>(labels, mask, SW, 64, 1, partial);
    loss_final<<<1, 64, 0, stream>>>(partial, B_N / 64, (float*)d_out);
  } else {
    int NS = 16;
    while (NS > 8 && base + (size_t)NS * B_N * 8 + 4096 > ws_size) NS >>= 1;
    int cps = B_N / NS;
    float2* partial = (float2*)(ws + base + (size_t)NS * B_N * 8);
    dim3 g2(B_N / 256, NS);
    gemm_kernel<<<g2, 256, 0, stream>>>(Ebf, W, SW, cps);
    loss_part<<<B_N / 64, 256, 0, stream>>>(labels, mask, SW, NS, 0, partial);
    loss_final<<<1, 64, 0, stream>>>(partial, B_N / 64, (float*)d_out);
  }
}

// Round 9
// 214.515 us; speedup vs baseline: 1.1814x; 1.1104x over previous
//
#include <hip/hip_runtime.h>
#include <hip/hip_bf16.h>

#define B_N 16384
#define D_K 128
#define NSYM 544   // 8 XCDs x 68 blocks (panels {x, 15-x} per XCD, 1040 tiles each)

typedef __bf16 bf16x8 __attribute__((ext_vector_type(8)));
typedef float f32x4 __attribute__((ext_vector_type(4)));
typedef float f32x2 __attribute__((ext_vector_type(2)));

#if defined(__has_builtin)
#if __has_builtin(__builtin_amdgcn_exp2f)
#define EXP2F(x) __builtin_amdgcn_exp2f(x)
#else
#define EXP2F(x) exp2f(x)
#endif
#else
#define EXP2F(x) exp2f(x)
#endif

__device__ __forceinline__ void gload_lds16(const void* g, void* l) {
  __builtin_amdgcn_global_load_lds(
      (const __attribute__((address_space(1))) unsigned int*)g,
      (__attribute__((address_space(3))) unsigned int*)l, 16, 0, 0);
}

// ---------------- kernel 1: normalize rows, prescale by sqrt(1/(T*ln2)), build col weights
__global__ __launch_bounds__(256) void prep_kernel(
    const float* __restrict__ E, const int* __restrict__ labels,
    const int* __restrict__ mask, __hip_bfloat16* __restrict__ Ebf,
    float2* __restrict__ W)
{
  int tid = threadIdx.x;
  int gtid = blockIdx.x * 256 + tid;
  if (gtid < B_N) {
    int lb = labels[gtid];
    float wm = (mask[gtid] != 0) ? 1.0f : 0.0f;
    W[gtid] = make_float2((lb == 0) ? wm : 0.0f, wm);
  }
  int lane = tid & 63;
  int wid = gtid >> 6;
  const float2* E2 = (const float2*)E;
  __hip_bfloat162* O2 = (__hip_bfloat162*)Ebf;
  for (int row = wid; row < B_N; row += 4096) {
    float2 v = E2[row * 64 + lane];
    float ss = v.x * v.x + v.y * v.y;
    #pragma unroll
    for (int m = 1; m < 64; m <<= 1) ss += __shfl_xor(ss, m);
    float sc = 3.7982826f / fmaxf(sqrtf(ss), 1e-12f);
    __hip_bfloat162 h;
    h.x = __float2bfloat16(v.x * sc);
    h.y = __float2bfloat16(v.y * sc);
    O2[row * 64 + lane] = h;
  }
}

// ---------------- symmetric tile body (R8-proven numerics)
template<bool DIAG, bool JSIDE>
__device__ __forceinline__ void tile_pair(
    const char* lds, const char* ldsW, const bf16x8 a[4][4],
    const f32x2 wRow[4][4], int C0loc, int colBase, int lane, int WR0,
    f32x2 accI[4][4], f32x2 cs[4])
{
  const int l15 = lane & 15, lg = lane >> 4, l7 = lane & 7;
  #pragma unroll
  for (int nf = 0; nf < 4; ++nf) {
    int col = nf * 16 + l15;
    int colg = colBase + C0loc + col;
    f32x2 wv = *(const f32x2*)(ldsW + ((C0loc + col) << 3));
    bf16x8 b[4];
    #pragma unroll
    for (int kk = 0; kk < 4; ++kk) {
      int addr = col * 256 + (((kk * 4 + lg) ^ l7) << 4);
      b[kk] = *(const bf16x8*)(lds + addr);
    }
    f32x4 c[4];
    __builtin_amdgcn_s_setprio(1);
    #pragma unroll
    for (int mf = 0; mf < 4; ++mf) {
      f32x4 t = {0.f, 0.f, 0.f, 0.f};
      #pragma unroll
      for (int kk = 0; kk < 4; ++kk)
        t = __builtin_amdgcn_mfma_f32_16x16x32_bf16(a[mf][kk], b[kk], t, 0, 0, 0);
      c[mf] = t;
    }
    __builtin_amdgcn_s_setprio(0);
    #pragma unroll
    for (int mf = 0; mf < 4; ++mf) {
      #pragma unroll
      for (int r = 0; r < 4; ++r) {
        float p = EXP2F(c[mf][r]);
        if (DIAG) {
          int rowg = WR0 + mf * 16 + lg * 4 + r;
          p = (rowg == colg) ? 0.0f : p;
        }
        accI[mf][r] += wv * p;                 // I-side row sums
        if (JSIDE) cs[nf] += wRow[mf][r] * p;  // J-side col sums
      }
    }
  }
}

// ---------------- kernel 2: symmetric Gram, XCD-pinned panels, R5 loop discipline
// XCD x (bid&7) owns column panels {x, 15-x} (2 MB of cols -> L2-resident).
// Block (I, c): rows of block I x panel c's 1024 cols, tiles t0..15 (t0 skips J<I).
// I-side (rows of I, w(col)-weighted) -> slot 4c+3.  J-side (rows of J>I,
// w(row)-weighted col sums, via per-wave LDS strips, no in-loop barrier) -> slot I.
// Coverage for row r in block R: slots s<R (J-side) + s>=R with s%4==3 (I-side).
__global__ __launch_bounds__(256, 2) void gemm_sym(
    const __hip_bfloat16* __restrict__ Ebf, const float2* __restrict__ W,
    float2* __restrict__ SW)
{
  __shared__ alignas(16) char smem[73728];
  char* ring = smem;                       // 2 x 16 KB tile double-buffer
  f32x2* strip = (f32x2*)(smem + 32768);   // 32 KB: [wave][1024 panel cols]
  char* ldsW = smem + 65536;               // 8 KB: w(col) for the panel

  const int tid = threadIdx.x;
  const int lane = tid & 63;
  const int w = tid >> 6;
  const int l15 = lane & 15, lg = lane >> 4;

  // ---- XCD-pinned decode: bid%8 = XCD (HW round-robin heuristic)
  const int x = blockIdx.x & 7, j = blockIdx.x >> 3;
  const int nA = 4 * x + 4;                // blocks in panel x
  const int c = (j < nA) ? x : (15 - x);
  const int I = (j < nA) ? j : (j - nA);

  const int panelBase = c << 10;           // first global col of panel (1024c)
  const int R0 = I << 8;
  const int WR0 = R0 + w * 64;
  const int kk0 = I - 4 * c;               // >=0 iff I lies inside this panel
  const int t0 = (kk0 > 0) ? (kk0 << 2) : 0;

  // ---- prologue: A fragments + row weights (amortized over up to 16 tiles)
  bf16x8 a[4][4];
  #pragma unroll
  for (int mf = 0; mf < 4; ++mf)
    #pragma unroll
    for (int kk = 0; kk < 4; ++kk) {
      int row = WR0 + mf * 16 + l15;
      a[mf][kk] = *(const bf16x8*)(Ebf + (size_t)row * D_K + kk * 32 + lg * 8);
    }
  f32x2 wRow[4][4];
  #pragma unroll
  for (int mf = 0; mf < 4; ++mf)
    #pragma unroll
    for (int r = 0; r < 4; ++r)
      wRow[mf][r] = *(const f32x2*)&W[WR0 + mf * 16 + lg * 4 + r];

  // staging offsets: linear LDS dest, swizzle on the GLOBAL source (m173)
  int goff[4], loff[4];
  #pragma unroll
  for (int i = 0; i < 4; ++i) {
    int q = i * 4 + w;
    int col = q * 4 + lg;
    int cc = l15 ^ (col & 7);
    goff[i] = col * D_K + cc * 8;
    loff[i] = q * 1024;
  }

  // stage panel W slice (8 KB) + tile t0; drain; rendezvous (R5 discipline)
  {
    const char* wsrc = (const char*)(W + panelBase);
    gload_lds16(wsrc + tid * 16, ldsW + tid * 16);
    gload_lds16(wsrc + (256 + tid) * 16, ldsW + (256 + tid) * 16);
    const __hip_bfloat16* s0p = Ebf + (size_t)(panelBase + (t0 << 6)) * D_K;
    #pragma unroll
    for (int i = 0; i < 4; ++i) gload_lds16(s0p + goff[i], ring + loff[i]);
  }
  asm volatile("s_waitcnt vmcnt(0)" ::: "memory");
  __builtin_amdgcn_s_barrier();

  f32x2 accI[4][4] = {};
  int cur = 0;
  for (int t = t0; t < 16; ++t) {
    if (t + 1 < 16) {   // prefetch next tile into the other buffer
      const __hip_bfloat16* src = Ebf + (size_t)(panelBase + ((t + 1) << 6)) * D_K;
      char* dst = ring + ((cur ^ 1) << 14);
      #pragma unroll
      for (int i = 0; i < 4; ++i) gload_lds16(src + goff[i], dst + loff[i]);
    }
    const char* lds = ring + (cur << 14);
    const int jb = 4 * c + (t >> 2);
    f32x2 cs[4] = {};
    if (jb == I) {
      tile_pair<true,  false>(lds, ldsW, a, wRow, t << 6, panelBase, lane, WR0, accI, cs);
    } else {
      tile_pair<false, true >(lds, ldsW, a, wRow, t << 6, panelBase, lane, WR0, accI, cs);
      // intra-wave col reduce -> this wave's own strip row (ds_write, NO barrier)
      #pragma unroll
      for (int nf = 0; nf < 4; ++nf) {
        float sx = cs[nf].x, sy = cs[nf].y;
        sx += __shfl_xor(sx, 16); sx += __shfl_xor(sx, 32);
        sy += __shfl_xor(sy, 16); sy += __shfl_xor(sy, 32);
        if (lg == nf) strip[w * 1024 + (t << 6) + nf * 16 + l15] = f32x2{sx, sy};
      }
    }
    asm volatile("s_waitcnt vmcnt(0)" ::: "memory");
    __builtin_amdgcn_s_barrier();
    cur ^= 1;
  }

  // ---- I-side write: slot 4c+3, rows of I
  #pragma unroll
  for (int mf = 0; mf < 4; ++mf) {
    #pragma unroll
    for (int r = 0; r < 4; ++r) {
      float s0 = accI[mf][r].x, tt = accI[mf][r].y;
      #pragma unroll
      for (int m = 1; m < 16; m <<= 1) {
        s0 += __shfl_xor(s0, m);
        tt += __shfl_xor(tt, m);
      }
      if (l15 == 0) {
        int rowg = WR0 + mf * 16 + lg * 4 + r;
        SW[(size_t)(4 * c + 3) * B_N + rowg] = make_float2(s0, tt);
      }
    }
  }

  // ---- J-side write: cross-wave strip sum, slot I (only cols of J-blocks > I)
  __syncthreads();
  for (int col = tid; col < 1024; col += 256) {
    int jb = 4 * c + (col >> 8);
    if (jb > I) {
      f32x2 s = strip[col];
      s += strip[1024 + col]; s += strip[2048 + col]; s += strip[3072 + col];
      SW[(size_t)I * B_N + panelBase + col] = make_float2(s.x, s.y);
    }
  }
}

// ---------------- fallback kernel 2 (R5 split version, tight-workspace only)
template<bool DIAG>
__device__ __forceinline__ void tile_compute(
    const char* lds, const char* ldsW, const bf16x8 a[4][4],
    int C0loc, int colBase, int lane, int WR0, f32x2 acc[4][4])
{
  const int l15 = lane & 15, lg = lane >> 4, l7 = lane & 7;
  #pragma unroll
  for (int nf = 0; nf < 4; ++nf) {
    int col = nf * 16 + l15;
    int colg = colBase + C0loc + col;
    f32x2 wv = *(const f32x2*)(ldsW + ((C0loc + col) << 3));
    bf16x8 b[4];
    #pragma unroll
    for (int kk = 0; kk < 4; ++kk) {
      int addr = col * 256 + (((kk * 4 + lg) ^ l7) << 4);
      b[kk] = *(const bf16x8*)(lds + addr);
    }
    f32x4 c[4];
    #pragma unroll
    for (int mf = 0; mf < 4; ++mf) {
      f32x4 t = {0.f, 0.f, 0.f, 0.f};
      #pragma unroll
      for (int kk = 0; kk < 4; ++kk)
        t = __builtin_amdgcn_mfma_f32_16x16x32_bf16(a[mf][kk], b[kk], t, 0, 0, 0);
      c[mf] = t;
    }
    #pragma unroll
    for (int mf = 0; mf < 4; ++mf) {
      #pragma unroll
      for (int r = 0; r < 4; ++r) {
        float p = EXP2F(c[mf][r]);
        if (DIAG) {
          int rowg = WR0 + mf * 16 + lg * 4 + r;
          p = (rowg == colg) ? 0.0f : p;
        }
        acc[mf][r] += wv * p;
      }
    }
  }
}

__global__ __launch_bounds__(256, 2) void gemm_kernel(
    const __hip_bfloat16* __restrict__ Ebf, const float2* __restrict__ W,
    float2* __restrict__ SW, int colsPerSplit)
{
  __shared__ alignas(16) char smem[65536];
  char* ldsW  = smem;
  char* tiles = smem + 16384;
  const int tid = threadIdx.x;
  const int lane = tid & 63;
  const int w = tid >> 6;
  const int R0 = blockIdx.x * 256;
  const int WR0 = R0 + w * 64;
  const int l15 = lane & 15, lg = lane >> 4;

  bf16x8 a[4][4];
  #pragma unroll
  for (int mf = 0; mf < 4; ++mf)
    #pragma unroll
    for (int kk = 0; kk < 4; ++kk) {
      int row = WR0 + mf * 16 + l15;
      a[mf][kk] = *(const bf16x8*)(Ebf + (size_t)row * D_K + kk * 32 + lg * 8);
    }
  int goff[4], loff[4];
  #pragma unroll
  for (int i = 0; i < 4; ++i) {
    int q = i * 4 + w;
    int col = q * 4 + lg;
    int cc = l15 ^ (col & 7);
    goff[i] = col * D_K + cc * 8;
    loff[i] = q * 1024;
  }
  f32x2 acc[4][4] = {};
  const int colBase = blockIdx.y * colsPerSplit;
  const int nt = colsPerSplit >> 6;
  {
    const char* wsrc = (const char*)(W + colBase);
    for (int i = tid; i < (colsPerSplit >> 1); i += 256)
      gload_lds16(wsrc + i * 16, ldsW + i * 16);
    const __hip_bfloat16* src0 = Ebf + (size_t)colBase * D_K;
    #pragma unroll
    for (int i = 0; i < 4; ++i) gload_lds16(src0 + goff[i], tiles + loff[i]);
  }
  asm volatile("s_waitcnt vmcnt(0)" ::: "memory");
  __builtin_amdgcn_s_barrier();
  int cur = 0;
  for (int t = 0; t < nt; ++t) {
    if (t + 1 < nt) {
      const __hip_bfloat16* src = Ebf + (size_t)(colBase + ((t + 1) << 6)) * D_K;
      #pragma unroll
      for (int i = 0; i < 4; ++i) gload_lds16(src + goff[i], tiles + ((cur ^ 1) << 14) + loff[i]);
    }
    const int C0loc = t << 6;
    const int Cg = colBase + C0loc;
    const bool diag = (Cg < R0 + 256) && (Cg + 64 > R0);
    if (diag) tile_compute<true >(tiles + (cur << 14), ldsW, a, C0loc, colBase, lane, WR0, acc);
    else      tile_compute<false>(tiles + (cur << 14), ldsW, a, C0loc, colBase, lane, WR0, acc);
    asm volatile("s_waitcnt vmcnt(0)" ::: "memory");
    __builtin_amdgcn_s_barrier();
    cur ^= 1;
  }
  #pragma unroll
  for (int mf = 0; mf < 4; ++mf) {
    #pragma unroll
    for (int r = 0; r < 4; ++r) {
      float s0 = acc[mf][r].x, tt = acc[mf][r].y;
      #pragma unroll
      for (int m = 1; m < 16; m <<= 1) { s0 += __shfl_xor(s0, m); tt += __shfl_xor(tt, m); }
      if (l15 == 0) {
        int rowg = WR0 + mf * 16 + lg * 4 + r;
        SW[(size_t)blockIdx.y * B_N + rowg] = make_float2(s0, tt);
      }
    }
  }
}

// ---------------- kernel 3a: per-row loss (symMode: read only written slots)
__global__ __launch_bounds__(256) void loss_part(
    const int* __restrict__ labels, const int* __restrict__ mask,
    const float2* __restrict__ SW, int NS, int symMode, float2* __restrict__ partial)
{
  __shared__ int sc0[4], sc1[4];
  __shared__ float st[4], sn[4];
  __shared__ float2 red[256];
  int tid = threadIdx.x, lane = tid & 63, wv = tid >> 6;

  int c0 = 0, c1 = 0;
  for (int i = tid; i < B_N; i += 256) {
    if (mask[i] != 0) { if (labels[i] == 0) c0++; else c1++; }
  }
  #pragma unroll
  for (int m = 1; m < 64; m <<= 1) { c0 += __shfl_xor(c0, m); c1 += __shfl_xor(c1, m); }
  if (lane == 0) { sc0[wv] = c0; sc1[wv] = c1; }
  __syncthreads();
  int cnt0 = sc0[0] + sc0[1] + sc0[2] + sc0[3];
  int cnt1 = sc1[0] + sc1[1] + sc1[2] + sc1[3];

  int r = blockIdx.x * 64 + (tid & 63);
  int q = tid >> 6;
  int R = r >> 8;
  float s0 = 0.f, tt = 0.f;
  for (int s = q; s < NS; s += 4) {
    bool use = symMode ? ((s < R) || (((s & 3) == 3) && s >= R)) : true;
    if (use) {
      float2 v = SW[(size_t)s * B_N + r];
      s0 += v.x; tt += v.y;
    }
  }
  red[tid] = make_float2(s0, tt);
  __syncthreads();

  float tot = 0.f, nv = 0.f;
  if (q == 0) {
    float2 va = red[tid], vb = red[64 + tid], vc = red[128 + tid], vd = red[192 + tid];
    s0 = va.x + vb.x + vc.x + vd.x;
    tt = va.y + vb.y + vc.y + vd.y;
    int lb = labels[r];
    float pos = (lb == 0) ? s0 : (tt - s0);
    int cnt = (lb == 0) ? cnt0 : cnt1;
    if (mask[r] != 0 && cnt > 1) {
      tot = logf(tt + 1e-8f) - logf(pos);
      nv = 1.f;
    }
  }
  #pragma unroll
  for (int m = 1; m < 64; m <<= 1) { tot += __shfl_xor(tot, m); nv += __shfl_xor(nv, m); }
  if (lane == 0) { st[wv] = tot; sn[wv] = nv; }
  __syncthreads();
  if (tid == 0) {
    partial[blockIdx.x] = make_float2(st[0] + st[1] + st[2] + st[3],
                                      sn[0] + sn[1] + sn[2] + sn[3]);
  }
}

// ---------------- kernel 3b: final deterministic reduce (one wave)
__global__ __launch_bounds__(64) void loss_final(
    const float2* __restrict__ partial, int nb, float* __restrict__ out)
{
  int lane = threadIdx.x;
  float t = 0.f, n = 0.f;
  for (int i = lane; i < nb; i += 64) {
    float2 v = partial[i];
    t += v.x; n += v.y;
  }
  #pragma unroll
  for (int m = 1; m < 64; m <<= 1) { t += __shfl_xor(t, m); n += __shfl_xor(n, m); }
  if (lane == 0) out[0] = (n > 0.f) ? t / fmaxf(n, 1.f) : 0.f;
}

extern "C" void kernel_launch(void* const* d_in, const int* in_sizes, int n_in,
                              void* d_out, int out_size, void* d_ws, size_t ws_size,
                              hipStream_t stream)
{
  const float* E = (const float*)d_in[0];
  const int* labels = (const int*)d_in[1];
  const int* mask = (const int*)d_in[2];

  char* ws = (char*)d_ws;
  __hip_bfloat16* Ebf = (__hip_bfloat16*)ws;                       // 4 MB
  float2* W = (float2*)(ws + (size_t)B_N * D_K * 2);               // 128 KB
  float2* SW = (float2*)(ws + (size_t)B_N * D_K * 2 + (size_t)B_N * 8);
  size_t base = (size_t)B_N * D_K * 2 + (size_t)B_N * 8;

  prep_kernel<<<1024, 256, 0, stream>>>(E, labels, mask, Ebf, W);

  size_t needSym = base + (size_t)64 * B_N * 8 + 4096;
  if (ws_size >= needSym) {
    float2* partial = (float2*)(ws + base + (size_t)64 * B_N * 8);
    gemm_sym<<<NSYM, 256, 0, stream>>>(Ebf, W, SW);
    loss_part<<<B_N / 64, 256, 0, stream>>>(labels, mask, SW, 64, 1, partial);
    loss_final<<<1, 64, 0, stream>>>(partial, B_N / 64, (float*)d_out);
  } else {
    int NS = 16;
    while (NS > 8 && base + (size_t)NS * B_N * 8 + 4096 > ws_size) NS >>= 1;
    int cps = B_N / NS;
    float2* partial = (float2*)(ws + base + (size_t)NS * B_N * 8);
    dim3 g2(B_N / 256, NS);
    gemm_kernel<<<g2, 256, 0, stream>>>(Ebf, W, SW, cps);
    loss_part<<<B_N / 64, 256, 0, stream>>>(labels, mask, SW, NS, 0, partial);
    loss_final<<<1, 64, 0, stream>>>(partial, B_N / 64, (float*)d_out);
  }
}

// Round 10
// 126.127 us; speedup vs baseline: 2.0093x; 1.7008x over previous
//
#include <hip/hip_runtime.h>
#include <hip/hip_bf16.h>

#define B_N 16384
#define D_K 128

typedef __bf16 bf16x8 __attribute__((ext_vector_type(8)));
typedef float f32x4 __attribute__((ext_vector_type(4)));
typedef float f32x2 __attribute__((ext_vector_type(2)));

#if defined(__has_builtin)
#if __has_builtin(__builtin_amdgcn_exp2f)
#define EXP2F(x) __builtin_amdgcn_exp2f(x)
#else
#define EXP2F(x) exp2f(x)
#endif
#else
#define EXP2F(x) exp2f(x)
#endif

__device__ __forceinline__ void gload_lds16(const void* g, void* l) {
  __builtin_amdgcn_global_load_lds(
      (const __attribute__((address_space(1))) unsigned int*)g,
      (__attribute__((address_space(3))) unsigned int*)l, 16, 0, 0);
}

// ---------------- kernel 1: normalize rows, prescale by sqrt(1/(T*ln2)), build col weights
__global__ __launch_bounds__(256) void prep_kernel(
    const float* __restrict__ E, const int* __restrict__ labels,
    const int* __restrict__ mask, __hip_bfloat16* __restrict__ Ebf,
    float2* __restrict__ W)
{
  int tid = threadIdx.x;
  int gtid = blockIdx.x * 256 + tid;
  if (gtid < B_N) {
    int lb = labels[gtid];
    float wm = (mask[gtid] != 0) ? 1.0f : 0.0f;
    W[gtid] = make_float2((lb == 0) ? wm : 0.0f, wm);
  }
  int lane = tid & 63;
  int wid = gtid >> 6;
  const float2* E2 = (const float2*)E;
  __hip_bfloat162* O2 = (__hip_bfloat162*)Ebf;
  for (int row = wid; row < B_N; row += 4096) {
    float2 v = E2[row * 64 + lane];
    float ss = v.x * v.x + v.y * v.y;
    #pragma unroll
    for (int m = 1; m < 64; m <<= 1) ss += __shfl_xor(ss, m);
    // sqrt(14.426950408889634) = sqrt(1/(0.1*ln2)); folded into both operands
    float sc = 3.7982826f / fmaxf(sqrtf(ss), 1e-12f);
    __hip_bfloat162 h;
    h.x = __float2bfloat16(v.x * sc);
    h.y = __float2bfloat16(v.y * sc);
    O2[row * 64 + lane] = h;
  }
}

// ---------------- kernel 2: fused Gram + exp + masked row-sum (R5-proven structure)
// Bank-conflict fix: chunk XOR widened l7 -> l15. Old read bank group =
// ((kk*4+lg)^l7)&7, independent of col -> 8 lanes per 4-bank group = 8-way
// conflict (2.94x, m136) on all 16 ds_read_b128/tile. New: chunk=(kk*4+lg)^l15
// -> (chunk&7) spreads over 8 values x 2 lanes = 2-way = free (1.02x).
// Staging source uses the matching inverse: c = l15 ^ (col&15)  (same-256B
// permutation -> coalescing unchanged; LDS chunk ci holds global chunk ci^(col&15),
// read recovers k-chunk = (kk*4+lg)^l15^l15 = kk*4+lg exactly as before).
template<bool DIAG>
__device__ __forceinline__ void tile_compute(
    const char* lds, const char* ldsW, const bf16x8 a[4][4],
    int C0loc, int colBase, int lane, int WR0, f32x2 acc[4][4])
{
  const int l15 = lane & 15, lg = lane >> 4;
  #pragma unroll
  for (int nf = 0; nf < 4; ++nf) {
    int col = nf * 16 + l15;
    int colg = colBase + C0loc + col;
    f32x2 wv = *(const f32x2*)(ldsW + ((C0loc + col) << 3));  // broadcast, conflict-free
    bf16x8 b[4];
    #pragma unroll
    for (int kk = 0; kk < 4; ++kk) {
      int addr = col * 256 + (((kk * 4 + lg) ^ l15) << 4);   // 2-way banks (was 8-way)
      b[kk] = *(const bf16x8*)(lds + addr);
    }
    f32x4 c[4];
    __builtin_amdgcn_s_setprio(1);
    #pragma unroll
    for (int mf = 0; mf < 4; ++mf) {
      f32x4 t = {0.f, 0.f, 0.f, 0.f};
      #pragma unroll
      for (int kk = 0; kk < 4; ++kk)
        t = __builtin_amdgcn_mfma_f32_16x16x32_bf16(a[mf][kk], b[kk], t, 0, 0, 0);
      c[mf] = t;
    }
    __builtin_amdgcn_s_setprio(0);
    #pragma unroll
    for (int mf = 0; mf < 4; ++mf) {
      #pragma unroll
      for (int r = 0; r < 4; ++r) {
        float p = EXP2F(c[mf][r]);     // exp(sim/T), scale folded into operands
        if (DIAG) {
          int rowg = WR0 + mf * 16 + lg * 4 + r;  // verified C/D layout
          p = (rowg == colg) ? 0.0f : p;
        }
        acc[mf][r] += wv * p;          // v_pk_fma_f32: (label-0 sum, total sum)
      }
    }
  }
}

// (256,2) = 256-reg unified budget; 64-row/wave live state ~160 regs.
// (256,3)/(256,4) spill catastrophically (R1/R3: FETCH 17MB -> 0.3-1.8GB).
__global__ __launch_bounds__(256, 2) void gemm_kernel(
    const __hip_bfloat16* __restrict__ Ebf, const float2* __restrict__ W,
    float2* __restrict__ SW, int colsPerSplit)
{
  __shared__ alignas(16) char smem[40960];
  char* ldsW  = smem;            // 8 KB: w(col) for cps<=1024
  char* tiles = smem + 8192;     // 2 x 16 KB double buffer

  const int tid = threadIdx.x;
  const int lane = tid & 63;
  const int w = tid >> 6;
  const int R0 = blockIdx.x * 256;
  const int WR0 = R0 + w * 64;
  const int l15 = lane & 15, lg = lane >> 4;

  // A fragments: 4 m-frags x 4 k-steps, held in VGPRs for the whole col loop
  bf16x8 a[4][4];
  #pragma unroll
  for (int mf = 0; mf < 4; ++mf)
    #pragma unroll
    for (int kk = 0; kk < 4; ++kk) {
      int row = WR0 + mf * 16 + l15;
      a[mf][kk] = *(const bf16x8*)(Ebf + (size_t)row * D_K + kk * 32 + lg * 8);
    }

  // staging offsets: linear LDS dest, inverse swizzle on the GLOBAL source (m173)
  int goff[4], loff[4];
  #pragma unroll
  for (int i = 0; i < 4; ++i) {
    int q = i * 4 + w;            // 1KB chunk-group id 0..15 (16KB tile)
    int col = q * 4 + lg;         // tile-local col this lane feeds (0..63)
    int cc = l15 ^ (col & 15);    // full 4-bit inverse swizzle (bank fix)
    goff[i] = col * D_K + cc * 8; // bf16 elements
    loff[i] = q * 1024;           // wave-uniform LDS base (bytes)
  }

  f32x2 acc[4][4] = {};
  const int colBase = blockIdx.y * colsPerSplit;
  const int nt = colsPerSplit >> 6;

  // prologue: stage W slice + tile 0, drain, rendezvous
  {
    const char* wsrc = (const char*)(W + colBase);
    for (int i = tid; i < (colsPerSplit >> 1); i += 256)
      gload_lds16(wsrc + i * 16, ldsW + i * 16);
    const __hip_bfloat16* src0 = Ebf + (size_t)colBase * D_K;
    #pragma unroll
    for (int i = 0; i < 4; ++i) gload_lds16(src0 + goff[i], tiles + loff[i]);
  }
  asm volatile("s_waitcnt vmcnt(0)" ::: "memory");
  __builtin_amdgcn_s_barrier();

  int cur = 0;
  for (int t = 0; t < nt; ++t) {
    if (t + 1 < nt) {   // prefetch next tile into the other buffer (2-phase)
      const __hip_bfloat16* src = Ebf + (size_t)(colBase + ((t + 1) << 6)) * D_K;
      char* dst = tiles + ((cur ^ 1) << 14);
      #pragma unroll
      for (int i = 0; i < 4; ++i) gload_lds16(src + goff[i], dst + loff[i]);
    }
    const int C0loc = t << 6;
    const int Cg = colBase + C0loc;
    const bool diag = (Cg < R0 + 256) && (Cg + 64 > R0);
    if (diag) tile_compute<true >(tiles + (cur << 14), ldsW, a, C0loc, colBase, lane, WR0, acc);
    else      tile_compute<false>(tiles + (cur << 14), ldsW, a, C0loc, colBase, lane, WR0, acc);
    asm volatile("s_waitcnt vmcnt(0)" ::: "memory");
    __builtin_amdgcn_s_barrier();
    cur ^= 1;
  }

  // reduce the 16 lanes (same row-group, different col subsets), then store
  #pragma unroll
  for (int mf = 0; mf < 4; ++mf) {
    #pragma unroll
    for (int r = 0; r < 4; ++r) {
      float s0 = acc[mf][r].x, tt = acc[mf][r].y;
      #pragma unroll
      for (int m = 1; m < 16; m <<= 1) {
        s0 += __shfl_xor(s0, m);
        tt += __shfl_xor(tt, m);
      }
      if (l15 == 0) {
        int rowg = WR0 + mf * 16 + lg * 4 + r;
        SW[(size_t)blockIdx.y * B_N + rowg] = make_float2(s0, tt);
      }
    }
  }
}

// ---------------- kernel 3a: per-row loss, 256 blocks x 64 rows, deterministic
__global__ __launch_bounds__(256) void loss_part(
    const int* __restrict__ labels, const int* __restrict__ mask,
    const float2* __restrict__ SW, int NS, float2* __restrict__ partial)
{
  __shared__ int sc0[4], sc1[4];
  __shared__ float st[4], sn[4];
  __shared__ float2 red[256];
  int tid = threadIdx.x, lane = tid & 63, wv = tid >> 6;

  // redundant full histogram per block (L2-resident, deterministic)
  int c0 = 0, c1 = 0;
  for (int i = tid; i < B_N; i += 256) {
    if (mask[i] != 0) { if (labels[i] == 0) c0++; else c1++; }
  }
  #pragma unroll
  for (int m = 1; m < 64; m <<= 1) { c0 += __shfl_xor(c0, m); c1 += __shfl_xor(c1, m); }
  if (lane == 0) { sc0[wv] = c0; sc1[wv] = c1; }
  __syncthreads();
  int cnt0 = sc0[0] + sc0[1] + sc0[2] + sc0[3];
  int cnt1 = sc1[0] + sc1[1] + sc1[2] + sc1[3];

  // 64 rows per block; 4 threads per row (slot quarters), fixed-order combine
  int r = blockIdx.x * 64 + (tid & 63);
  int q = tid >> 6;
  float s0 = 0.f, tt = 0.f;
  for (int s = q; s < NS; s += 4) {
    float2 v = SW[(size_t)s * B_N + r];
    s0 += v.x; tt += v.y;
  }
  red[tid] = make_float2(s0, tt);
  __syncthreads();

  float tot = 0.f, nv = 0.f;
  if (q == 0) {
    float2 va = red[tid], vb = red[64 + tid], vc = red[128 + tid], vd = red[192 + tid];
    s0 = va.x + vb.x + vc.x + vd.x;
    tt = va.y + vb.y + vc.y + vd.y;
    int lb = labels[r];
    float pos = (lb == 0) ? s0 : (tt - s0);
    int cnt = (lb == 0) ? cnt0 : cnt1;
    if (mask[r] != 0 && cnt > 1) {
      // den = pos + neg = tt (diag excluded); loss = log(den+EPS) - log(pos)
      tot = logf(tt + 1e-8f) - logf(pos);
      nv = 1.f;
    }
  }
  #pragma unroll
  for (int m = 1; m < 64; m <<= 1) { tot += __shfl_xor(tot, m); nv += __shfl_xor(nv, m); }
  if (lane == 0) { st[wv] = tot; sn[wv] = nv; }
  __syncthreads();
  if (tid == 0) {
    partial[blockIdx.x] = make_float2(st[0] + st[1] + st[2] + st[3],
                                      sn[0] + sn[1] + sn[2] + sn[3]);
  }
}

// ---------------- kernel 3b: final deterministic reduce (one wave)
__global__ __launch_bounds__(64) void loss_final(
    const float2* __restrict__ partial, int nb, float* __restrict__ out)
{
  int lane = threadIdx.x;
  float t = 0.f, n = 0.f;
  for (int i = lane; i < nb; i += 64) {
    float2 v = partial[i];
    t += v.x; n += v.y;
  }
  #pragma unroll
  for (int m = 1; m < 64; m <<= 1) { t += __shfl_xor(t, m); n += __shfl_xor(n, m); }
  if (lane == 0) out[0] = (n > 0.f) ? t / fmaxf(n, 1.f) : 0.f;
}

extern "C" void kernel_launch(void* const* d_in, const int* in_sizes, int n_in,
                              void* d_out, int out_size, void* d_ws, size_t ws_size,
                              hipStream_t stream)
{
  const float* E = (const float*)d_in[0];
  const int* labels = (const int*)d_in[1];
  const int* mask = (const int*)d_in[2];

  char* ws = (char*)d_ws;
  __hip_bfloat16* Ebf = (__hip_bfloat16*)ws;                       // 4 MB
  float2* W = (float2*)(ws + (size_t)B_N * D_K * 2);               // 128 KB
  float2* SW = (float2*)(ws + (size_t)B_N * D_K * 2 + (size_t)B_N * 8);
  size_t base = (size_t)B_N * D_K * 2 + (size_t)B_N * 8;

  int NS = 16;  // col splits; shrink if workspace tight (ldsW sized for cps<=1024)
  while (NS > 1 && base + (size_t)NS * B_N * 8 + 4096 > ws_size) NS >>= 1;
  int cps = B_N / NS;
  float2* partial = (float2*)(ws + base + (size_t)NS * B_N * 8);

  prep_kernel<<<1024, 256, 0, stream>>>(E, labels, mask, Ebf, W);
  dim3 g2(B_N / 256, NS);
  gemm_kernel<<<g2, 256, 0, stream>>>(Ebf, W, SW, cps);
  loss_part<<<B_N / 64, 256, 0, stream>>>(labels, mask, SW, NS, partial);
  loss_final<<<1, 64, 0, stream>>>(partial, B_N / 64, (float*)d_out);
}